// Round 5
// baseline (31008.646 us; speedup 1.0000x reference)
//
#include <hip/hip_runtime.h>

// Problem constants
#define T_SEQ   8192
#define N_RES   2048
#define K_IN    512

// Geometry: 128 blocks x 256 threads (4 waves); 16 rows/block, 4 rows/wave.
#define G_BLOCKS 128
#define B_THREADS 256
#define ROWS_PER_WAVE 4
#define ROWS_PER_BLOCK 16
static_assert(G_BLOCKS * ROWS_PER_BLOCK == N_RES, "row partition mismatch");

#define INV_SQRT_N 0.022097086912079612f

// Phase encoding: packet float e = phi*(v + ENC_OFF), phi alternates per ring
// generation (phi(g) = ((g>>1)&1) ? -1 : +1, slot = g&1). |v| <= 0.0222 so
// |e| in [0.078, 0.122]. Ready iff phi_expected*e > ENC_THR; stale (gen-2)
// packet has opposite phi -> not-ready; zero-init -> not-ready.
#define ENC_OFF 0.1f
#define ENC_THR 0.05f

typedef unsigned long long u64;
typedef unsigned int u32;

__device__ __forceinline__ float fast_tanh(float v) {
    float e = __expf(2.0f * v);
    return 1.0f - 2.0f / (e + 1.0f);
}

#define KEEP4(v) asm("" : "+v"((v).x), "+v"((v).y), "+v"((v).z), "+v"((v).w))

// d_ws layout: ring [2][1024] u64 (16 KB) | flags u32[128] (512 B)
__global__ __launch_bounds__(B_THREADS, 1)
void reservoir_v5(const float* __restrict__ input,   // [T_SEQ][K_IN]
                  const float* __restrict__ state0,  // [N_RES]
                  const float* __restrict__ W_in,    // [N_RES][K_IN]
                  const float* __restrict__ W_res,   // [N_RES][N_RES]
                  float* __restrict__ out,           // [T_SEQ+1][N_RES]
                  u64* __restrict__ ring,
                  u32* __restrict__ flags)
{
    const int tid  = threadIdx.x;
    const int lane = tid & 63;
    const int wave = tid >> 6;
    const int blk  = blockIdx.x;
    const int r0   = blk * ROWS_PER_BLOCK + wave * ROWS_PER_WAVE;

    __shared__ float s_lds[2][N_RES];   // double-buffered state (16 KB)

    // ---- persistent weights: lane l owns cols {4l+256i} ----
    float4 wr[ROWS_PER_WAVE][8];
    float4 wi[ROWS_PER_WAVE][2];
    #pragma unroll
    for (int k = 0; k < ROWS_PER_WAVE; ++k) {
        const float* rrow = W_res + (size_t)(r0 + k) * N_RES;
        #pragma unroll
        for (int i = 0; i < 8; ++i)
            wr[k][i] = *reinterpret_cast<const float4*>(rrow + 4 * lane + 256 * i);
        const float* irow = W_in + (size_t)(r0 + k) * K_IN;
        #pragma unroll
        for (int i = 0; i < 2; ++i)
            wi[k][i] = *reinterpret_cast<const float4*>(irow + 4 * lane + 256 * i);
    }

    // out row 0 = initial state
    if (blk == 0)
        for (int j = tid; j < N_RES; j += B_THREADS) out[j] = state0[j];

    // s_0 -> LDS buffer 0 (covered by the in-loop __syncthreads at t=0)
    #pragma unroll
    for (int i = 0; i < 8; ++i)
        s_lds[0][i * 256 + tid] = state0[i * 256 + tid];

    // x row 0 (layout matches wi columns {4l+256i})
    float4 xa = *reinterpret_cast<const float4*>(input + 4 * lane);
    float4 xb = *reinterpret_cast<const float4*>(input + 4 * lane + 256);

    for (int t = 0; t < T_SEQ; ++t) {
        const int buf = t & 1;

        // issue x_{t+1} prefetch early; latency hides under gate+compute
        float4 xna = xa, xnb = xb;
        if (t + 1 < T_SEQ) {
            const float* xr = input + (size_t)(t + 1) * K_IN;
            xna = *reinterpret_cast<const float4*>(xr + 4 * lane);
            xnb = *reinterpret_cast<const float4*>(xr + 4 * lane + 256);
        }

        if (t > 0) {
            // ---- gate: wave 0 polls the 128-flag array (8 lines/round) ----
            if (wave == 0) {
                const u64* fp = reinterpret_cast<const u64*>(flags);
                for (;;) {
                    u64 f = __hip_atomic_load(fp + lane, __ATOMIC_RELAXED,
                                              __HIP_MEMORY_SCOPE_AGENT);
                    bool mine = ((u32)f >= (u32)t) && ((u32)(f >> 32) >= (u32)t);
                    if (__all(mine)) break;
                    __builtin_amdgcn_s_sleep(2);
                }
            }
            __syncthreads();   // release waves 1-3; all flags >= t observed

            // ---- single-round data read (guaranteed ready; retry = safety net) ----
            const u64* rp = ring + (buf << 10);
            const float phi = ((t >> 1) & 1) ? -1.0f : 1.0f;
            float2 sv2[4];
            u32 pend = 0xFu;
            do {
                #pragma unroll
                for (int i = 0; i < 4; ++i) {
                    if (pend & (1u << i)) {
                        u64 e = __hip_atomic_load(rp + i * 256 + tid,
                                                  __ATOMIC_RELAXED, __HIP_MEMORY_SCOPE_AGENT);
                        float lo = __uint_as_float((u32)e);
                        float hi = __uint_as_float((u32)(e >> 32));
                        if (phi * lo > ENC_THR && phi * hi > ENC_THR) {
                            sv2[i] = make_float2(fmaf(phi, lo, -ENC_OFF),
                                                 fmaf(phi, hi, -ENC_OFF));
                            pend &= ~(1u << i);
                        }
                    }
                }
                if (pend) __builtin_amdgcn_s_sleep(1);
            } while (pend);
            #pragma unroll
            for (int i = 0; i < 4; ++i)
                *reinterpret_cast<float2*>(&s_lds[buf][2 * (i * 256 + tid)]) = sv2[i];
        }
        __syncthreads();

        // ---- input contribution ----
        float acc[ROWS_PER_WAVE];
        #pragma unroll
        for (int k = 0; k < ROWS_PER_WAVE; ++k) {
            float a = 0.0f;
            a = fmaf(wi[k][0].x, xa.x, a); a = fmaf(wi[k][0].y, xa.y, a);
            a = fmaf(wi[k][0].z, xa.z, a); a = fmaf(wi[k][0].w, xa.w, a);
            a = fmaf(wi[k][1].x, xb.x, a); a = fmaf(wi[k][1].y, xb.y, a);
            a = fmaf(wi[k][1].z, xb.z, a); a = fmaf(wi[k][1].w, xb.w, a);
            acc[k] = a;
        }

        // ---- state contribution from LDS ----
        float4 sv[8];
        #pragma unroll
        for (int i = 0; i < 8; ++i)
            sv[i] = *reinterpret_cast<const float4*>(&s_lds[buf][4 * lane + 256 * i]);
        #pragma unroll
        for (int k = 0; k < ROWS_PER_WAVE; ++k) {
            float a = acc[k];
            #pragma unroll
            for (int i = 0; i < 8; ++i) {
                a = fmaf(wr[k][i].x, sv[i].x, a);
                a = fmaf(wr[k][i].y, sv[i].y, a);
                a = fmaf(wr[k][i].z, sv[i].z, a);
                a = fmaf(wr[k][i].w, sv[i].w, a);
            }
            acc[k] = a;
        }

        // ---- full-wave butterfly reduce (4 rows in flight) ----
        #pragma unroll
        for (int off = 32; off > 0; off >>= 1) {
            #pragma unroll
            for (int k = 0; k < ROWS_PER_WAVE; ++k)
                acc[k] += __shfl_xor(acc[k], off, 64);
        }

        // ---- finalize: ring publish on critical path; out store deferred ----
        const float v0 = fast_tanh(acc[0]) * INV_SQRT_N;
        const float v1 = fast_tanh(acc[1]) * INV_SQRT_N;
        const float v2 = fast_tanh(acc[2]) * INV_SQRT_N;
        const float v3 = fast_tanh(acc[3]) * INV_SQRT_N;
        const int   slotn = (t + 1) & 1;
        const float phin  = (((t + 1) >> 1) & 1) ? -1.0f : 1.0f;
        if (lane == 0) {
            u64 pk = (u64)__float_as_uint(phin * (v0 + ENC_OFF)) |
                     ((u64)__float_as_uint(phin * (v1 + ENC_OFF)) << 32);
            __hip_atomic_store(ring + (slotn << 10) + (r0 >> 1), pk,
                               __ATOMIC_RELAXED, __HIP_MEMORY_SCOPE_AGENT);
        } else if (lane == 1) {
            u64 pk = (u64)__float_as_uint(phin * (v2 + ENC_OFF)) |
                     ((u64)__float_as_uint(phin * (v3 + ENC_OFF)) << 32);
            __hip_atomic_store(ring + (slotn << 10) + (r0 >> 1) + 1, pk,
                               __ATOMIC_RELAXED, __HIP_MEMORY_SCOPE_AGENT);
        }

        // drain: every wave's ring stores ACKed at the coherence point
        __syncthreads();

        // flag store (tid 0) strictly after all ring stores are at L3
        if (tid == 0)
            __hip_atomic_store(&flags[blk], (u32)(t + 1),
                               __ATOMIC_RELAXED, __HIP_MEMORY_SCOPE_AGENT);
        // out store off the critical path; drains under next gate wait
        if (tid == 2)
            *reinterpret_cast<float4*>(out + (size_t)(t + 1) * N_RES + r0) =
                make_float4(v0, v1, v2, v3);

        // ---- pin weights across the back edge ----
        #pragma unroll
        for (int k = 0; k < ROWS_PER_WAVE; ++k) {
            #pragma unroll
            for (int i = 0; i < 8; ++i) KEEP4(wr[k][i]);
            KEEP4(wi[k][0]); KEEP4(wi[k][1]);
        }

        xa = xna; xb = xnb;
    }
}

extern "C" void kernel_launch(void* const* d_in, const int* in_sizes, int n_in,
                              void* d_out, int out_size, void* d_ws, size_t ws_size,
                              hipStream_t stream) {
    const float* input  = (const float*)d_in[0];
    const float* state0 = (const float*)d_in[1];
    const float* W_in   = (const float*)d_in[2];
    const float* W_res  = (const float*)d_in[3];
    float* out = (float*)d_out;
    u64* ring  = (u64*)d_ws;
    u32* flags = (u32*)((char*)d_ws + 2 * (N_RES / 2) * sizeof(u64));

    // zero = "not ready" for ring phases and flags; re-cleared on every call
    hipMemsetAsync(d_ws, 0, 2 * (N_RES / 2) * sizeof(u64) + G_BLOCKS * sizeof(u32),
                   stream);

    void* args[] = { (void*)&input, (void*)&state0, (void*)&W_in, (void*)&W_res,
                     (void*)&out, (void*)&ring, (void*)&flags };
    hipLaunchCooperativeKernel((const void*)reservoir_v5,
                               dim3(G_BLOCKS), dim3(B_THREADS),
                               args, 0, stream);
}

// Round 6
// 21562.682 us; speedup vs baseline: 1.4381x; 1.4381x over previous
//
#include <hip/hip_runtime.h>

// Problem constants
#define T_SEQ   8192
#define N_RES   2048
#define K_IN    512

// Geometry: 64 blocks x 512 threads (8 waves); 32 rows/block, 4 rows/wave.
#define G_BLOCKS 64
#define B_THREADS 512
#define ROWS_PER_WAVE 4
#define ROWS_PER_BLOCK 32
static_assert(G_BLOCKS * ROWS_PER_BLOCK == N_RES, "row partition mismatch");

#define INV_SQRT_N 0.022097086912079612f

// Phase encoding: packet float e = phi*(v + ENC_OFF), phi alternates per ring
// generation (phi(g) = ((g>>1)&1) ? -1 : +1, slot = g&1). |v| <= 0.0222 so
// |e| in [0.078, 0.122]. Ready iff phi_expected*e > ENC_THR; stale (gen-2)
// packet has opposite phi -> not-ready; zero-init -> not-ready.
#define ENC_OFF 0.1f
#define ENC_THR 0.05f

typedef unsigned long long u64;
typedef unsigned int u32;

__device__ __forceinline__ float fast_tanh(float v) {
    float e = __expf(2.0f * v);
    return 1.0f - 2.0f / (e + 1.0f);
}

// In-loop register pin: the "+v" OUTPUT is the only def reaching next
// iteration's uses, so the compiler cannot re-load the value from memory.
#define KEEP4(v) asm("" : "+v"((v).x), "+v"((v).y), "+v"((v).z), "+v"((v).w))

// d_ws layout: ring [2][1024] u64 (16 KB)
__global__ __launch_bounds__(B_THREADS, 2)
void reservoir_v6(const float* __restrict__ input,   // [T_SEQ][K_IN]
                  const float* __restrict__ state0,  // [N_RES]
                  const float* __restrict__ W_in,    // [N_RES][K_IN]
                  const float* __restrict__ W_res,   // [N_RES][N_RES]
                  float* __restrict__ out,           // [T_SEQ+1][N_RES]
                  u64* __restrict__ ring)
{
    const int tid  = threadIdx.x;
    const int lane = tid & 63;
    const int wave = tid >> 6;
    const int blk  = blockIdx.x;
    const int r0   = blk * ROWS_PER_BLOCK + wave * ROWS_PER_WAVE;

    __shared__ float s_lds[2][N_RES];   // double-buffered state (16 KB)

    // ---- persistent weights: lane l owns cols {4l+256i} ----
    float4 wr[ROWS_PER_WAVE][8];
    float4 wi[ROWS_PER_WAVE][2];
    #pragma unroll
    for (int k = 0; k < ROWS_PER_WAVE; ++k) {
        const float* rrow = W_res + (size_t)(r0 + k) * N_RES;
        #pragma unroll
        for (int i = 0; i < 8; ++i)
            wr[k][i] = *reinterpret_cast<const float4*>(rrow + 4 * lane + 256 * i);
        const float* irow = W_in + (size_t)(r0 + k) * K_IN;
        #pragma unroll
        for (int i = 0; i < 2; ++i)
            wi[k][i] = *reinterpret_cast<const float4*>(irow + 4 * lane + 256 * i);
    }

    // out row 0 = initial state
    if (blk == 0)
        for (int j = tid; j < N_RES; j += B_THREADS) out[j] = state0[j];

    // s_0 -> LDS buffer 0 (covered by the in-loop __syncthreads at t=0)
    #pragma unroll
    for (int i = 0; i < 4; ++i)
        s_lds[0][i * 512 + tid] = state0[i * 512 + tid];

    // x row 0 (layout matches wi columns {4l+256i}; waves redundantly load -> L1 hit)
    float4 xa = *reinterpret_cast<const float4*>(input + 4 * lane);
    float4 xb = *reinterpret_cast<const float4*>(input + 4 * lane + 256);

    for (int t = 0; t < T_SEQ; ++t) {
        const int buf = t & 1;

        // issue x_{t+1} prefetch before the spin so HBM latency hides under it
        float4 xna = xa, xnb = xb;
        if (t + 1 < T_SEQ) {
            const float* xr = input + (size_t)(t + 1) * K_IN;
            xna = *reinterpret_cast<const float4*>(xr + 4 * lane);
            xnb = *reinterpret_cast<const float4*>(xr + 4 * lane + 256);
        }

        if (t > 0) {
            // ---- paced coalesced poll: 2 u64/thread covers the 1024-entry slot ----
            const u64* rp = ring + (buf << 10);
            const float phi = ((t >> 1) & 1) ? -1.0f : 1.0f;
            float2 sv2[2];
            u32 pend = 0x3u;
            while (pend) {
                #pragma unroll
                for (int i = 0; i < 2; ++i) {
                    if (pend & (1u << i)) {
                        u64 e = __hip_atomic_load(rp + i * 512 + tid,
                                                  __ATOMIC_RELAXED, __HIP_MEMORY_SCOPE_AGENT);
                        float lo = __uint_as_float((u32)e);
                        float hi = __uint_as_float((u32)(e >> 32));
                        if (phi * lo > ENC_THR && phi * hi > ENC_THR) {
                            sv2[i] = make_float2(fmaf(phi, lo, -ENC_OFF),
                                                 fmaf(phi, hi, -ENC_OFF));
                            pend &= ~(1u << i);
                        }
                    }
                }
                if (pend) __builtin_amdgcn_s_sleep(1);   // ~64cy backoff
            }
            #pragma unroll
            for (int i = 0; i < 2; ++i)
                *reinterpret_cast<float2*>(&s_lds[buf][2 * (i * 512 + tid)]) = sv2[i];
        }
        __syncthreads();

        // ---- input contribution ----
        float acc[ROWS_PER_WAVE];
        #pragma unroll
        for (int k = 0; k < ROWS_PER_WAVE; ++k) {
            float a = 0.0f;
            a = fmaf(wi[k][0].x, xa.x, a); a = fmaf(wi[k][0].y, xa.y, a);
            a = fmaf(wi[k][0].z, xa.z, a); a = fmaf(wi[k][0].w, xa.w, a);
            a = fmaf(wi[k][1].x, xb.x, a); a = fmaf(wi[k][1].y, xb.y, a);
            a = fmaf(wi[k][1].z, xb.z, a); a = fmaf(wi[k][1].w, xb.w, a);
            acc[k] = a;
        }

        // ---- state contribution from LDS (layout proven conflict-free) ----
        float4 sv[8];
        #pragma unroll
        for (int i = 0; i < 8; ++i)
            sv[i] = *reinterpret_cast<const float4*>(&s_lds[buf][4 * lane + 256 * i]);
        #pragma unroll
        for (int k = 0; k < ROWS_PER_WAVE; ++k) {
            float a = acc[k];
            #pragma unroll
            for (int i = 0; i < 8; ++i) {
                a = fmaf(wr[k][i].x, sv[i].x, a);
                a = fmaf(wr[k][i].y, sv[i].y, a);
                a = fmaf(wr[k][i].z, sv[i].z, a);
                a = fmaf(wr[k][i].w, sv[i].w, a);
            }
            acc[k] = a;
        }

        // ---- full-wave butterfly reduce (4 rows in flight) ----
        #pragma unroll
        for (int off = 32; off > 0; off >>= 1) {
            #pragma unroll
            for (int k = 0; k < ROWS_PER_WAVE; ++k)
                acc[k] += __shfl_xor(acc[k], off, 64);
        }

        // ---- finalize: publish first (critical path), out store off-path ----
        const float v0 = fast_tanh(acc[0]) * INV_SQRT_N;
        const float v1 = fast_tanh(acc[1]) * INV_SQRT_N;
        const float v2 = fast_tanh(acc[2]) * INV_SQRT_N;
        const float v3 = fast_tanh(acc[3]) * INV_SQRT_N;
        const int   slotn = (t + 1) & 1;
        const float phin  = (((t + 1) >> 1) & 1) ? -1.0f : 1.0f;
        if (lane == 0) {
            u64 pk = (u64)__float_as_uint(phin * (v0 + ENC_OFF)) |
                     ((u64)__float_as_uint(phin * (v1 + ENC_OFF)) << 32);
            __hip_atomic_store(ring + (slotn << 10) + (r0 >> 1), pk,
                               __ATOMIC_RELAXED, __HIP_MEMORY_SCOPE_AGENT);
        } else if (lane == 1) {
            u64 pk = (u64)__float_as_uint(phin * (v2 + ENC_OFF)) |
                     ((u64)__float_as_uint(phin * (v3 + ENC_OFF)) << 32);
            __hip_atomic_store(ring + (slotn << 10) + (r0 >> 1) + 1, pk,
                               __ATOMIC_RELAXED, __HIP_MEMORY_SCOPE_AGENT);
        } else if (lane == 2) {
            // per-wave out store (rows r0..r0+3) — MUST be lane-scoped, not tid-scoped
            *reinterpret_cast<float4*>(out + (size_t)(t + 1) * N_RES + r0) =
                make_float4(v0, v1, v2, v3);
        }

        // ---- pin weights across the back edge (defeats reload/remat) ----
        #pragma unroll
        for (int k = 0; k < ROWS_PER_WAVE; ++k) {
            #pragma unroll
            for (int i = 0; i < 8; ++i) KEEP4(wr[k][i]);
            KEEP4(wi[k][0]); KEEP4(wi[k][1]);
        }

        xa = xna; xb = xnb;
    }
}

extern "C" void kernel_launch(void* const* d_in, const int* in_sizes, int n_in,
                              void* d_out, int out_size, void* d_ws, size_t ws_size,
                              hipStream_t stream) {
    const float* input  = (const float*)d_in[0];
    const float* state0 = (const float*)d_in[1];
    const float* W_in   = (const float*)d_in[2];
    const float* W_res  = (const float*)d_in[3];
    float* out = (float*)d_out;
    u64* ring  = (u64*)d_ws;

    // zero = "not ready" for both phases; re-cleared on every call/replay
    hipMemsetAsync(d_ws, 0, 2 * (N_RES / 2) * sizeof(u64), stream);

    void* args[] = { (void*)&input, (void*)&state0, (void*)&W_in, (void*)&W_res,
                     (void*)&out, (void*)&ring };
    hipLaunchCooperativeKernel((const void*)reservoir_v6,
                               dim3(G_BLOCKS), dim3(B_THREADS),
                               args, 0, stream);
}